// Round 3
// baseline (693.018 us; speedup 1.0000x reference)
//
#include <hip/hip_runtime.h>
#include <math.h>

#define E_TOTAL 8
#define NUM_LOCAL 4
#define HIDDEN 1024
#define FFN 4096
#define CAP 2048

typedef unsigned short ushort_t;
typedef __attribute__((ext_vector_type(8))) short short8;     // 8 bf16 (4 VGPRs)
typedef __attribute__((ext_vector_type(8))) unsigned short u16x8;
typedef __attribute__((ext_vector_type(16))) float f32x16;    // 32x32 MFMA acc

__device__ __forceinline__ unsigned short f2bf(float f) {
  unsigned int u = __float_as_uint(f);
  u += 0x7FFFu + ((u >> 16) & 1u);   // round-to-nearest-even
  return (unsigned short)(u >> 16);
}

__device__ __forceinline__ void gload_lds16(const void* g, void* l) {
  __builtin_amdgcn_global_load_lds(
      (const __attribute__((address_space(1))) void*)g,
      (__attribute__((address_space(3))) void*)l,
      16, 0, 0);
}

// ---- fp32 -> bf16 converts ----
// fused: x + w0 + w3 in one dispatch (makes cvt cost visible in rocprof
// top-5 and drops 2 launches). 8 elems/lane.
__global__ __launch_bounds__(256) void cvt3_kernel(
    const float4* __restrict__ x, const float4* __restrict__ w0,
    const float4* __restrict__ w3, u16x8* __restrict__ xb,
    u16x8* __restrict__ w0b, u16x8* __restrict__ w3b) {
  const int NX8 = E_TOTAL * CAP * HIDDEN / 8;  // 2,097,152 lanes
  const int NW8 = E_TOTAL * FFN * HIDDEN / 8;  // 4,194,304 lanes
  const int i = blockIdx.x * 256 + threadIdx.x;
  const float4* s;
  u16x8* d;
  int j;
  if (i < NX8) { s = x; d = xb; j = i; }
  else if (i < NX8 + NW8) { s = w0; d = w0b; j = i - NX8; }
  else { s = w3; d = w3b; j = i - NX8 - NW8; }
  float4 a = s[2 * (size_t)j], b = s[2 * (size_t)j + 1];
  u16x8 o;
  o[0] = f2bf(a.x); o[1] = f2bf(a.y); o[2] = f2bf(a.z); o[3] = f2bf(a.w);
  o[4] = f2bf(b.x); o[5] = f2bf(b.y); o[6] = f2bf(b.z); o[7] = f2bf(b.w);
  d[j] = o;
}

// single-tensor cvt (fallback path when ws < 288 MB forces aliasing)
__global__ __launch_bounds__(256) void cvt_kernel(const float4* __restrict__ s,
                                                  u16x8* __restrict__ d) {
  const size_t i = (size_t)blockIdx.x * 256 + threadIdx.x;
  float4 a = s[2 * i], b = s[2 * i + 1];
  u16x8 o;
  o[0] = f2bf(a.x); o[1] = f2bf(a.y); o[2] = f2bf(a.z); o[3] = f2bf(a.w);
  o[4] = f2bf(b.x); o[5] = f2bf(b.y); o[6] = f2bf(b.z); o[7] = f2bf(b.w);
  d[i] = o;
}

// NT GEMM: A [E][M][K] bf16 row-major, B [E][N][K] bf16 row-major (B^T),
// C[e][m][n] = sum_k A*B.
// 128x128 block tile, BK=64, 4 waves each owning 64x64 as a 2x2 grid of
// 32x32 tiles via v_mfma_f32_32x32x16_bf16 (m119: higher pipe ceiling than
// 16x16x32; half the MFMA instruction count per iter, same ds_read count).
// LDS rows are 128B (all alias bank 0) -> rotate swizzle on 16B slots:
// slot s of row r holds global k-chunk (s + r) & 7; reads of chunk c use
// slot (c - r) & 7 -> every read phase spreads over all 8 bank-groups
// (round-2 measured: SQ_LDS_BANK_CONFLICT = 0 with this scheme).
template <int M, int N, int K, bool GELU_OUT>
__global__ __launch_bounds__(256, 2) void gemm_nt(
    const ushort_t* __restrict__ A, const ushort_t* __restrict__ B,
    void* __restrict__ Cout, const float* __restrict__ ot, int d0) {
  __shared__ ushort_t lds_a[128 * 64];  // 16 KB row-major [128][64], swizzled
  __shared__ ushort_t lds_b[128 * 64];  // 32 KB total -> LDS allows 5 blk/CU

  const int e = blockIdx.z;
  const int bm = blockIdx.x * 128;
  const int bn = blockIdx.y * 128;
  const int t = threadIdx.x;
  const int wave = t >> 6, lane = t & 63;
  const int wr = wave >> 1, wc = wave & 1;  // wave quadrant in 128x128
  const int l32 = lane & 31, h5 = lane >> 5;
  const int r8 = lane >> 3;                 // staging: row within 8-row group
  const int s8 = lane & 7;                  // staging: LDS slot within row
  const int g8 = (s8 + r8) & 7;             // staging: swizzled global chunk

  const ushort_t* Ag = A + (size_t)e * M * K + (size_t)(bm + r8) * K + g8 * 8;
  const ushort_t* Bg = B + (size_t)e * N * K + (size_t)(bn + r8) * K + g8 * 8;

  f32x16 acc[2][2];
#pragma unroll
  for (int i = 0; i < 2; ++i)
#pragma unroll
    for (int j = 0; j < 2; ++j)
#pragma unroll
      for (int r = 0; r < 16; ++r) acc[i][j][r] = 0.f;

  for (int kb = 0; kb < K / 64; ++kb) {
    // ---- stage 128x64 A and B tiles ----
    // One global_load_lds(16B): 8 rows x 128B, lane-contiguous LDS dest.
    const size_t ko = (size_t)kb * 64;
#pragma unroll
    for (int j = 0; j < 4; ++j) {
      const int R = (j * 4 + wave) * 8;   // R&7==0 keeps swizzle consistent
      gload_lds16(Ag + ko + (size_t)R * K, &lds_a[R * 64]);
      gload_lds16(Bg + ko + (size_t)R * K, &lds_b[R * 64]);
    }
    __syncthreads();

#pragma unroll
    for (int ks = 0; ks < 4; ++ks) {  // 4 k-steps of 16
      // A operand 32x32x16: m = lane&31, k = (lane>>5)*8 + j  -> 16B chunk
      // c = ks*2 + h5 of row m (swizzled slot (c - row) & 7). B symmetric.
      const int c = ks * 2 + h5;
      short8 af[2], bfr[2];
#pragma unroll
      for (int mi = 0; mi < 2; ++mi) {
        const int ra = wr * 64 + mi * 32 + l32;
        const int rb = wc * 64 + mi * 32 + l32;
        af[mi]  = *(const short8*)&lds_a[ra * 64 + ((c - ra) & 7) * 8];
        bfr[mi] = *(const short8*)&lds_b[rb * 64 + ((c - rb) & 7) * 8];
      }
#pragma unroll
      for (int mi = 0; mi < 2; ++mi)
#pragma unroll
        for (int ni = 0; ni < 2; ++ni)
          acc[mi][ni] = __builtin_amdgcn_mfma_f32_32x32x16_bf16(
              af[mi], bfr[ni], acc[mi][ni], 0, 0, 0);
    }
    __syncthreads();
  }

  // ---- epilogue: 32x32 C/D layout col=lane&31,
  // row=(reg&3)+8*(reg>>2)+4*(lane>>5)  (m74/m101-verified) ----
  if (GELU_OUT) {
    ushort_t* C = (ushort_t*)Cout + (size_t)e * M * N;
#pragma unroll
    for (int mi = 0; mi < 2; ++mi)
#pragma unroll
      for (int ni = 0; ni < 2; ++ni) {
        const int rbase = bm + wr * 64 + mi * 32;
        const int cbase = bn + wc * 64 + ni * 32;
#pragma unroll
        for (int r = 0; r < 16; ++r) {
          const int row = rbase + (r & 3) + 8 * (r >> 2) + 4 * h5;
          float v = acc[mi][ni][r];
          v = 0.5f * v * (1.f + erff(v * 0.70710678118654752f));  // exact GELU
          C[(size_t)row * N + cbase + l32] = f2bf(v);
        }
      }
  } else {
    float mask = 1.f;
    if (e >= NUM_LOCAL) {
      float s = 0.f;
      for (int b = 0; b < d0; ++b) s += ot[b * E_TOTAL + e];
      mask = (s != 0.f) ? 1.f : 0.f;
    }
    float* C = (float*)Cout + (size_t)e * M * N;
#pragma unroll
    for (int mi = 0; mi < 2; ++mi)
#pragma unroll
      for (int ni = 0; ni < 2; ++ni) {
        const int rbase = bm + wr * 64 + mi * 32;
        const int cbase = bn + wc * 64 + ni * 32;
#pragma unroll
        for (int r = 0; r < 16; ++r) {
          const int row = rbase + (r & 3) + 8 * (r >> 2) + 4 * h5;
          C[(size_t)row * N + cbase + l32] = acc[mi][ni][r] * mask;
        }
      }
  }
}

extern "C" void kernel_launch(void* const* d_in, const int* in_sizes, int n_in,
                              void* d_out, int out_size, void* d_ws,
                              size_t ws_size, hipStream_t stream) {
  const float* ot = (const float*)d_in[0];   // [D0][E] gating activity
  const float* x  = (const float*)d_in[1];   // [D0][E][CAP][HIDDEN] fp32
  const float* w0 = (const float*)d_in[2];   // [E][FFN][HIDDEN] fp32
  const float* w3 = (const float*)d_in[3];   // [E][HIDDEN][FFN] fp32
  const int d0 = in_sizes[0] / E_TOTAL;

  char* ws = (char*)d_ws;
  const size_t MB = 1024 * 1024;
  const int nx = E_TOTAL * CAP * HIDDEN;  // 16.8M elements
  const int nw = E_TOTAL * FFN * HIDDEN;  // 33.6M elements

  if (ws_size >= 288 * MB) {
    // non-aliased layout: xb[0,32) w0b[32,96) w3b[96,160) h[160,288) MB
    ushort_t* xb  = (ushort_t*)ws;
    ushort_t* w0b = (ushort_t*)(ws + 32 * MB);
    ushort_t* w3b = (ushort_t*)(ws + 96 * MB);
    ushort_t* h   = (ushort_t*)(ws + 160 * MB);

    cvt3_kernel<<<(nx + 2 * nw) / (256 * 8), 256, 0, stream>>>(
        (const float4*)x, (const float4*)w0, (const float4*)w3,
        (u16x8*)xb, (u16x8*)w0b, (u16x8*)w3b);

    gemm_nt<CAP, FFN, HIDDEN, true>
        <<<dim3(CAP / 128, FFN / 128, E_TOTAL), 256, 0, stream>>>(
            xb, w0b, h, nullptr, d0);
    gemm_nt<CAP, HIDDEN, FFN, false>
        <<<dim3(CAP / 128, HIDDEN / 128, E_TOTAL), 256, 0, stream>>>(
            h, w3b, d_out, ot, d0);
  } else {
    // aliased fallback (224 MB): xb[0,32) reused as w3b after GEMM1;
    // w0b[32,96); h[96,224)
    ushort_t* xb  = (ushort_t*)ws;
    ushort_t* w0b = (ushort_t*)(ws + 32 * MB);
    ushort_t* w3b = (ushort_t*)ws;
    ushort_t* h   = (ushort_t*)(ws + 96 * MB);

    cvt_kernel<<<nx / (256 * 8), 256, 0, stream>>>((const float4*)x,
                                                   (u16x8*)xb);
    cvt_kernel<<<nw / (256 * 8), 256, 0, stream>>>((const float4*)w0,
                                                   (u16x8*)w0b);
    gemm_nt<CAP, FFN, HIDDEN, true>
        <<<dim3(CAP / 128, FFN / 128, E_TOTAL), 256, 0, stream>>>(
            xb, w0b, h, nullptr, d0);
    cvt_kernel<<<nw / (256 * 8), 256, 0, stream>>>((const float4*)w3,
                                                   (u16x8*)w3b);
    gemm_nt<CAP, HIDDEN, FFN, false>
        <<<dim3(CAP / 128, HIDDEN / 128, E_TOTAL), 256, 0, stream>>>(
            h, w3b, d_out, ot, d0);
  }
}